// Round 8
// baseline (193.517 us; speedup 1.0000x reference)
//
#include <hip/hip_runtime.h>

typedef __attribute__((ext_vector_type(8))) short short8;
typedef __attribute__((ext_vector_type(4))) short short4v;
typedef __attribute__((ext_vector_type(4))) float f32x4;
typedef __attribute__((ext_vector_type(16))) float f32x16;
typedef __attribute__((ext_vector_type(2))) unsigned int u32x2;

#define MFMA16x32(A, B, C) \
  __builtin_amdgcn_mfma_f32_16x16x32_bf16((A), (B), (C), 0, 0, 0)
#define MFMA32x16(A, B, C) \
  __builtin_amdgcn_mfma_f32_32x32x16_bf16((A), (B), (C), 0, 0, 0)

// 32x32x8 bf16 (legacy 2-reg A/B). B-operand k = 4*(lane>>5)+j matches the
// 32x32 S^T C/D reg-quad layout -> packed P feeds PV directly from registers.
#if defined(__has_builtin)
#if __has_builtin(__builtin_amdgcn_mfma_f32_32x32x8bf16_1k)
#define HAVE_32X8 1
#endif
#endif
__device__ __forceinline__ f32x16 mfma32x8(short4v a, short4v b, f32x16 c) {
#ifdef HAVE_32X8
  return __builtin_amdgcn_mfma_f32_32x32x8bf16_1k(a, b, c, 0, 0, 0);
#else
  f32x16 d;
  asm("v_mfma_f32_32x32x8_bf16 %0, %1, %2, %3"
      : "=v"(d)
      : "v"(a), "v"(b), "v"(c));
  return d;
#endif
}

// Async global->LDS, 16B/lane, offset=0 ONLY (non-zero imm offset was the
// R6/R7 correctness bug suspect — never again). LDS dest is the WAVE-UNIFORM
// base (HW scatters lane i -> base + i*16).
__device__ __forceinline__ void async_cp16(const unsigned short* g, void* l) {
  __builtin_amdgcn_global_load_lds(
      (const __attribute__((address_space(1))) unsigned int*)g,
      (__attribute__((address_space(3))) unsigned int*)l, 16, 0, 0);
}

__device__ __forceinline__ unsigned int fbits(float f) {
  return __builtin_bit_cast(unsigned int, f);
}
// pack two floats -> two bf16 (truncate): low ushort = a, high = b
__device__ __forceinline__ unsigned int pack_bf16(float a, float b) {
  return __builtin_amdgcn_perm(fbits(b), fbits(a), 0x07060302u);
}
__device__ __forceinline__ unsigned short bf16_rne(float f) {
  unsigned int u = fbits(f);
  return (unsigned short)((u + 0x8000u) >> 16);
}
__device__ __forceinline__ float lk(float x) { return fmaxf(x, 0.2f * x); }

// ---------------------------------------------------------------------------
// Kernel 0: prep = xconv (blocks 0..4095) + wtrans (blocks 4096..4287).
// ---------------------------------------------------------------------------
__global__ __launch_bounds__(256) void prep_kernel(
    const float* __restrict__ x, const float* __restrict__ Wq,
    const float* __restrict__ Wk, const float* __restrict__ Wv,
    unsigned short* __restrict__ xb, unsigned short* __restrict__ WT) {
  const int bid = blockIdx.x;
  if (bid < 4096) {
    const size_t i = ((size_t)bid * 256 + threadIdx.x) * 4;
    const float4 f = *(const float4*)(x + i);
    u32x2 u = {
        (unsigned int)bf16_rne(f.x) | ((unsigned int)bf16_rne(f.y) << 16),
        (unsigned int)bf16_rne(f.z) | ((unsigned int)bf16_rne(f.w) << 16)};
    *(u32x2*)(xb + i) = u;
    return;
  }
  __shared__ float tile[32][33];
  const int wb = bid - 4096;
  const int g = wb / 64, rem = wb % 64;
  const int k0 = (rem >> 3) * 32, n0 = (rem & 7) * 32;
  const float* W = (g == 0) ? Wq : (g == 1) ? Wk : Wv;
  const int t = threadIdx.x;
  {
    const int kr = t >> 3, nc = (t & 7) * 4;
    const float4 f = *(const float4*)(W + (size_t)(k0 + kr) * 256 + n0 + nc);
    tile[kr][nc + 0] = f.x; tile[kr][nc + 1] = f.y;
    tile[kr][nc + 2] = f.z; tile[kr][nc + 3] = f.w;
  }
  __syncthreads();
  {
    const int nr = t >> 3, kc = (t & 7) * 4;
    unsigned int u0 = (unsigned int)bf16_rne(tile[kc + 0][nr]) |
                      ((unsigned int)bf16_rne(tile[kc + 1][nr]) << 16);
    unsigned int u1 = (unsigned int)bf16_rne(tile[kc + 2][nr]) |
                      ((unsigned int)bf16_rne(tile[kc + 3][nr]) << 16);
    u32x2 u = {u0, u1};
    *(u32x2*)(WT + (size_t)g * 65536 + (size_t)(n0 + nr) * 256 + k0 + kc) = u;
  }
}

// ---------------------------------------------------------------------------
// Kernel 1: fused QKV projection GEMM (unchanged — passed R5).
// ---------------------------------------------------------------------------
__global__ __launch_bounds__(256, 2) void proj_kernel(
    const unsigned short* __restrict__ xb, const unsigned short* __restrict__ WT,
    unsigned short* __restrict__ QH, unsigned short* __restrict__ KH,
    unsigned short* __restrict__ VT) {
  __shared__ __align__(16) char smem[65536];  // dbuf x (A 16K + B 16K)
  const int tid = threadIdx.x;
  const int w = tid >> 6, lane = tid & 63, l15 = lane & 15, quad = lane >> 4;
  const int bid = blockIdx.x;
  const int mtile = bid / 6, nt = bid % 6;
  const int g = nt >> 1, n0 = (nt & 1) * 128;
  const int m0 = mtile * 128;

  const int srow = lane >> 3, useg = lane & 7;
  const int swz = (useg ^ srow) * 8;  // shorts
  const unsigned short* aSj[4];
  const unsigned short* bSj[4];
#pragma unroll
  for (int j = 0; j < 4; j++) {
    aSj[j] = xb + (size_t)(m0 + w * 32 + j * 8 + srow) * 256 + swz;
    bSj[j] = WT + (size_t)g * 65536 +
             (size_t)(n0 + w * 32 + j * 8 + srow) * 256 + swz;
  }

#pragma unroll
  for (int j = 0; j < 4; j++) {  // preload k-tile 0 -> buf 0
    async_cp16(aSj[j], smem + w * 4096 + j * 1024);
    async_cp16(bSj[j], smem + 16384 + w * 4096 + j * 1024);
  }
  __syncthreads();

  const f32x4 zero = {0.f, 0.f, 0.f, 0.f};
  f32x4 acc[2][8];
#pragma unroll
  for (int s = 0; s < 2; s++)
#pragma unroll
    for (int c = 0; c < 8; c++) acc[s][c] = zero;

  const int sega = ((quad) ^ (l15 & 7)) * 16;
  int aoff[2], boff[8];
#pragma unroll
  for (int s = 0; s < 2; s++) aoff[s] = (w * 32 + s * 16 + l15) * 128;
#pragma unroll
  for (int c = 0; c < 8; c++) boff[c] = 16384 + (c * 16 + l15) * 128;

#pragma unroll
  for (int t = 0; t < 4; t++) {
    const int nb = t & 1;
    const int kn = ((t + 1) & 3) * 64;
#pragma unroll
    for (int j = 0; j < 4; j++) {
      async_cp16(aSj[j] + kn, smem + (nb ^ 1) * 32768 + w * 4096 + j * 1024);
      async_cp16(bSj[j] + kn,
                 smem + (nb ^ 1) * 32768 + 16384 + w * 4096 + j * 1024);
    }
#pragma unroll
    for (int ks = 0; ks < 2; ks++) {
      const int sg = ks ? (sega ^ 64) : sega;
      short8 af[2], bf[8];
#pragma unroll
      for (int s = 0; s < 2; s++)
        af[s] = *(const short8*)(smem + nb * 32768 + aoff[s] + sg);
#pragma unroll
      for (int c = 0; c < 8; c++)
        bf[c] = *(const short8*)(smem + nb * 32768 + boff[c] + sg);
      if (g < 2) {
#pragma unroll
        for (int s = 0; s < 2; s++)
#pragma unroll
          for (int c = 0; c < 8; c++)
            acc[s][c] = MFMA16x32(bf[c], af[s], acc[s][c]);  // swapped
      } else {
#pragma unroll
        for (int s = 0; s < 2; s++)
#pragma unroll
          for (int c = 0; c < 8; c++)
            acc[s][c] = MFMA16x32(af[s], bf[c], acc[s][c]);
      }
    }
    __syncthreads();
  }

  if (g < 2) {
    unsigned short* O = g ? KH : QH;
    const float sc = g ? 1.0f : 0.17677669529663688f;  // 1/sqrt(32) into Q
#pragma unroll
    for (int s = 0; s < 2; s++)
#pragma unroll
      for (int c = 0; c < 8; c++) {
        const int row = m0 + w * 32 + s * 16 + l15;
        const int col = n0 + c * 16 + quad * 4;
        const int bb = row >> 12, nn = row & 4095;
        const int hh = col >> 5, dl = col & 31;
        u32x2 pk = {pack_bf16(acc[s][c][0] * sc, acc[s][c][1] * sc),
                    pack_bf16(acc[s][c][2] * sc, acc[s][c][3] * sc)};
        *(u32x2*)(O + ((size_t)(bb * 8 + hh) * 4096 + nn) * 32 + dl) = pk;
      }
  } else {
#pragma unroll
    for (int s = 0; s < 2; s++)
#pragma unroll
      for (int c = 0; c < 8; c++) {
        const int col = n0 + c * 16 + l15;  // h*32 + d
        const int hh = col >> 5, dl = col & 31;
        const int row = m0 + w * 32 + s * 16 + quad * 4;
        const int bb = row >> 12, nn = row & 4095;
        u32x2 pk = {pack_bf16(acc[s][c][0], acc[s][c][1]),
                    pack_bf16(acc[s][c][2], acc[s][c][3])};
        *(u32x2*)(VT + (size_t)((bb * 8 + hh) * 32 + dl) * 4096 + nn) = pk;
      }
  }
}

// ---------------------------------------------------------------------------
// Kernel 2: attention. Block = 256 thr (4 waves), one (b,h) x 128 q; wave owns
// 32 q. Grid 1024 = 32 bh x 32 q-tiles. 4 blocks/CU.
// Iter = 128 keys: K-tile 8KB [key][4x16B segs, phys subseg p holds global
// seg p^(key&3)], V-tile 8.125KB [d][128key] + 16B pad per 4-row group; both
// staged via explicit per-instruction pointers (offset=0 global_load_lds
// only) into dbuf LDS. All frag reads are base+imm. S^T = K.Q^T (2x
// 32x32x16); leaky+pack in regs; packed reg-quads feed 32x32x8 PV directly.
// ---------------------------------------------------------------------------
__global__ __launch_bounds__(256, 4) void attn_kernel(
    const unsigned short* __restrict__ QH, const unsigned short* __restrict__ KH,
    const unsigned short* __restrict__ VT, float* __restrict__ out) {
  constexpr int VREG = 8192;           // V region offset within a buffer
  constexpr int BUF = 8192 + 8 * 1040; // K 8KB + V 8x1040B = 16512
  __shared__ __align__(16) char smem[2 * BUF];
  const int tid = threadIdx.x;
  const int w = tid >> 6, lane = tid & 63, l31 = lane & 31, half = lane >> 5;
  const int bid = blockIdx.x;
  const int bh = bid & 31, qt = bid >> 5;  // XCD swizzle: bh fixed per XCD
  const int b = bh >> 3, h = bh & 7;
  const int qbase = qt * 128 + w * 32;     // 32 q per wave, q < 4096

  // Q frags: B-operand of 32x32x16: n=q=l31, k(d) = kh*16 + half*8 + j.
  const unsigned short* Qp =
      QH + ((size_t)bh * 4096 + qbase + l31) * 32 + half * 8;
  short8 qf[2];
  qf[0] = *(const short8*)(Qp);
  qf[1] = *(const short8*)(Qp + 16);

  // --- staging sources (lane-permuted, one pointer per instruction) ---
  // K j=0: phys seg w*128+lane (key=seg>>2, subseg sl=lane&3) <- global seg
  //        sl^(key&3) of that key. j=1: key+16 (same &3 -> same subseg map).
  const int key0 = (w * 128 + lane) >> 2, sl0 = lane & 3;
  const unsigned short* gK0 =
      KH + ((size_t)bh * 4096 + key0) * 32 + (sl0 ^ (key0 & 3)) * 8;
  const unsigned short* gK1 = gK0 + 16 * 32;  // key0+16
  // V: group G = w*2+j (4 rows x 256B contiguous; +16B pad between groups in
  //    LDS only). lane: d = G*4 + (lane>>4), key seg = lane&15.
  const int d0 = w * 8 + (lane >> 4);
  const int sv = lane & 15;
  const unsigned short* gV0 = VT + ((size_t)bh * 32 + d0) * 4096 + sv * 8;
  const unsigned short* gV1 = gV0 + 4 * 4096;
  const int ldsK = w * 2048;
  const int ldsV0 = VREG + (w * 2) * 1040;
  const int ldsV1 = VREG + (w * 2 + 1) * 1040;

  // --- hoisted read bases (all frag reads = base + imm) ---
  // kb0 phys subseg p=half^(l31&3) -> holds global seg half (d=half*8+..).
  // kb1=kb0^32 -> p^2 -> global seg half+2 (d=16+half*8+..).
  const int kb0 = l31 * 64 + ((half ^ (l31 & 3)) * 16);
  const int kb1 = kb0 ^ 32;
  const int vb = VREG + l31 * 256 + (l31 >> 2) * 16 + half * 8;

  // preload tile 0 -> buf 0
  async_cp16(gK0, smem + ldsK);
  async_cp16(gK1, smem + ldsK + 1024);
  async_cp16(gV0, smem + ldsV0);
  async_cp16(gV1, smem + ldsV1);
  gK0 += 4096;  // 128 keys * 32 shorts
  gK1 += 4096;
  gV0 += 128;   // 128 keys
  gV1 += 128;
  __syncthreads();

  f32x16 z16, acc;
#pragma unroll
  for (int i = 0; i < 16; i++) { z16[i] = 0.f; acc[i] = 0.f; }

#define ATTN_BODY(B_)                                                         \
  {                                                                           \
    async_cp16(gK0, smem + ((B_) ^ 1) * BUF + ldsK);                          \
    async_cp16(gK1, smem + ((B_) ^ 1) * BUF + ldsK + 1024);                   \
    async_cp16(gV0, smem + ((B_) ^ 1) * BUF + ldsV0);                         \
    async_cp16(gV1, smem + ((B_) ^ 1) * BUF + ldsV1);                         \
    gK0 += 4096;                                                              \
    gK1 += 4096;                                                              \
    gV0 += 128;                                                               \
    gV1 += 128;                                                               \
    const char* Bc = smem + (B_)*BUF;                                         \
    _Pragma("unroll") for (int kt = 0; kt < 4; kt++) {                        \
      short8 kf0 = *(const short8*)(Bc + kt * 2048 + kb0);                    \
      short8 kf1 = *(const short8*)(Bc + kt * 2048 + kb1);                    \
      short4v vf[4];                                                          \
      _Pragma("unroll") for (int g = 0; g < 4; g++) vf[g] =                   \
          *(const short4v*)(Bc + vb + (kt * 4 + g) * 16);                     \
      f32x16 st = MFMA32x16(kf0, qf[0], z16);                                 \
      st = MFMA32x16(kf1, qf[1], st);                                         \
      _Pragma("unroll") for (int g = 0; g < 4; g++) {                         \
        u32x2 pk = {pack_bf16(lk(st[4 * g + 0]), lk(st[4 * g + 1])),          \
                    pack_bf16(lk(st[4 * g + 2]), lk(st[4 * g + 3]))};         \
        acc = mfma32x8(vf[g], __builtin_bit_cast(short4v, pk), acc);          \
      }                                                                       \
    }                                                                         \
    __syncthreads();                                                          \
  }

  for (int it = 0; it < 32; it += 2) {
    ATTN_BODY(0)
    ATTN_BODY(1)
  }
#undef ATTN_BODY

  // Epilogue: O^T row=d=8g+4*half+(reg&3), col=q=l31 -> f32x4 stores.
#pragma unroll
  for (int g = 0; g < 4; g++) {
    f32x4 o = {acc[4 * g + 0], acc[4 * g + 1], acc[4 * g + 2], acc[4 * g + 3]};
    *(f32x4*)(out + ((size_t)b * 4096 + qbase + l31) * 256 + h * 32 + g * 8 +
              half * 4) = o;
  }
}

// ---------------------------------------------------------------------------
extern "C" void kernel_launch(void* const* d_in, const int* in_sizes, int n_in,
                              void* d_out, int out_size, void* d_ws,
                              size_t ws_size, hipStream_t stream) {
  const float* x = (const float*)d_in[0];
  const float* Wq = (const float*)d_in[1];
  const float* Wk = (const float*)d_in[2];
  const float* Wv = (const float*)d_in[3];
  float* out = (float*)d_out;

  // Workspace (bf16): QH | KH | VT | xb | WT  (~33.5 MB). Order matters:
  // attn's final wrap-prefetch reads a few KB past KH/VT ends -> must land in
  // the next ws region (KH->VT, VT->xb), never past ws.
  unsigned short* ws = (unsigned short*)d_ws;
  unsigned short* QHb = ws;                // 32 bh * 4096 n * 32 d
  unsigned short* KHb = ws + 4194304;      // 32 bh * 4096 n * 32 d
  unsigned short* VTb = ws + 2 * 4194304;  // 32 bh * 32 d * 4096 n
  unsigned short* xbb = ws + 3 * 4194304;  // 16384*256
  unsigned short* WTb = ws + 4 * 4194304;  // 3 * 256 * 256

  prep_kernel<<<4288, 256, 0, stream>>>(x, Wq, Wk, Wv, xbb, WTb);
  proj_kernel<<<768, 256, 0, stream>>>(xbb, WTb, QHb, KHb, VTb);
  attn_kernel<<<1024, 256, 0, stream>>>(QHb, KHb, VTb, out);
}

// Round 9
// 184.300 us; speedup vs baseline: 1.0500x; 1.0500x over previous
//
#include <hip/hip_runtime.h>

typedef __attribute__((ext_vector_type(8))) short short8;
typedef __attribute__((ext_vector_type(4))) short short4v;
typedef __attribute__((ext_vector_type(4))) float f32x4;
typedef __attribute__((ext_vector_type(16))) float f32x16;
typedef __attribute__((ext_vector_type(2))) unsigned int u32x2;

#define MFMA16x32(A, B, C) \
  __builtin_amdgcn_mfma_f32_16x16x32_bf16((A), (B), (C), 0, 0, 0)
#define MFMA32x16(A, B, C) \
  __builtin_amdgcn_mfma_f32_32x32x16_bf16((A), (B), (C), 0, 0, 0)

// 32x32x8 bf16 (legacy 2-reg A/B). B-operand k = 4*(lane>>5)+j matches the
// 32x32 S^T C/D reg-quad layout -> packed P feeds PV directly from registers.
#if defined(__has_builtin)
#if __has_builtin(__builtin_amdgcn_mfma_f32_32x32x8bf16_1k)
#define HAVE_32X8 1
#endif
#endif
__device__ __forceinline__ f32x16 mfma32x8(short4v a, short4v b, f32x16 c) {
#ifdef HAVE_32X8
  return __builtin_amdgcn_mfma_f32_32x32x8bf16_1k(a, b, c, 0, 0, 0);
#else
  f32x16 d;
  asm("v_mfma_f32_32x32x8_bf16 %0, %1, %2, %3"
      : "=v"(d)
      : "v"(a), "v"(b), "v"(c));
  return d;
#endif
}

// Async global->LDS, 16B/lane, offset=0 ONLY (non-zero imm offset was the
// R6/R7 correctness bug). LDS dest is the WAVE-UNIFORM base
// (HW scatters lane i -> base + i*16).
__device__ __forceinline__ void async_cp16(const unsigned short* g, void* l) {
  __builtin_amdgcn_global_load_lds(
      (const __attribute__((address_space(1))) unsigned int*)g,
      (__attribute__((address_space(3))) unsigned int*)l, 16, 0, 0);
}

__device__ __forceinline__ unsigned int fbits(float f) {
  return __builtin_bit_cast(unsigned int, f);
}
// pack two floats -> two bf16 (truncate): low ushort = a, high = b
__device__ __forceinline__ unsigned int pack_bf16(float a, float b) {
  return __builtin_amdgcn_perm(fbits(b), fbits(a), 0x07060302u);
}
__device__ __forceinline__ unsigned short bf16_rne(float f) {
  unsigned int u = fbits(f);
  return (unsigned short)((u + 0x8000u) >> 16);
}
__device__ __forceinline__ float lk(float x) { return fmaxf(x, 0.2f * x); }

// ---------------------------------------------------------------------------
// Kernel 0: prep = xconv (blocks 0..4095) + wtrans (blocks 4096..4287).
// ---------------------------------------------------------------------------
__global__ __launch_bounds__(256) void prep_kernel(
    const float* __restrict__ x, const float* __restrict__ Wq,
    const float* __restrict__ Wk, const float* __restrict__ Wv,
    unsigned short* __restrict__ xb, unsigned short* __restrict__ WT) {
  const int bid = blockIdx.x;
  if (bid < 4096) {
    const size_t i = ((size_t)bid * 256 + threadIdx.x) * 4;
    const float4 f = *(const float4*)(x + i);
    u32x2 u = {
        (unsigned int)bf16_rne(f.x) | ((unsigned int)bf16_rne(f.y) << 16),
        (unsigned int)bf16_rne(f.z) | ((unsigned int)bf16_rne(f.w) << 16)};
    *(u32x2*)(xb + i) = u;
    return;
  }
  __shared__ float tile[32][33];
  const int wb = bid - 4096;
  const int g = wb / 64, rem = wb % 64;
  const int k0 = (rem >> 3) * 32, n0 = (rem & 7) * 32;
  const float* W = (g == 0) ? Wq : (g == 1) ? Wk : Wv;
  const int t = threadIdx.x;
  {
    const int kr = t >> 3, nc = (t & 7) * 4;
    const float4 f = *(const float4*)(W + (size_t)(k0 + kr) * 256 + n0 + nc);
    tile[kr][nc + 0] = f.x; tile[kr][nc + 1] = f.y;
    tile[kr][nc + 2] = f.z; tile[kr][nc + 3] = f.w;
  }
  __syncthreads();
  {
    const int nr = t >> 3, kc = (t & 7) * 4;
    unsigned int u0 = (unsigned int)bf16_rne(tile[kc + 0][nr]) |
                      ((unsigned int)bf16_rne(tile[kc + 1][nr]) << 16);
    unsigned int u1 = (unsigned int)bf16_rne(tile[kc + 2][nr]) |
                      ((unsigned int)bf16_rne(tile[kc + 3][nr]) << 16);
    u32x2 u = {u0, u1};
    *(u32x2*)(WT + (size_t)g * 65536 + (size_t)(n0 + nr) * 256 + k0 + kc) = u;
  }
}

// ---------------------------------------------------------------------------
// Kernel 1: fused QKV projection GEMM (unchanged — passed R5/R8).
// ---------------------------------------------------------------------------
__global__ __launch_bounds__(256, 2) void proj_kernel(
    const unsigned short* __restrict__ xb, const unsigned short* __restrict__ WT,
    unsigned short* __restrict__ QH, unsigned short* __restrict__ KH,
    unsigned short* __restrict__ VT) {
  __shared__ __align__(16) char smem[65536];  // dbuf x (A 16K + B 16K)
  const int tid = threadIdx.x;
  const int w = tid >> 6, lane = tid & 63, l15 = lane & 15, quad = lane >> 4;
  const int bid = blockIdx.x;
  const int mtile = bid / 6, nt = bid % 6;
  const int g = nt >> 1, n0 = (nt & 1) * 128;
  const int m0 = mtile * 128;

  const int srow = lane >> 3, useg = lane & 7;
  const int swz = (useg ^ srow) * 8;  // shorts
  const unsigned short* aSj[4];
  const unsigned short* bSj[4];
#pragma unroll
  for (int j = 0; j < 4; j++) {
    aSj[j] = xb + (size_t)(m0 + w * 32 + j * 8 + srow) * 256 + swz;
    bSj[j] = WT + (size_t)g * 65536 +
             (size_t)(n0 + w * 32 + j * 8 + srow) * 256 + swz;
  }

#pragma unroll
  for (int j = 0; j < 4; j++) {  // preload k-tile 0 -> buf 0
    async_cp16(aSj[j], smem + w * 4096 + j * 1024);
    async_cp16(bSj[j], smem + 16384 + w * 4096 + j * 1024);
  }
  __syncthreads();

  const f32x4 zero = {0.f, 0.f, 0.f, 0.f};
  f32x4 acc[2][8];
#pragma unroll
  for (int s = 0; s < 2; s++)
#pragma unroll
    for (int c = 0; c < 8; c++) acc[s][c] = zero;

  const int sega = ((quad) ^ (l15 & 7)) * 16;
  int aoff[2], boff[8];
#pragma unroll
  for (int s = 0; s < 2; s++) aoff[s] = (w * 32 + s * 16 + l15) * 128;
#pragma unroll
  for (int c = 0; c < 8; c++) boff[c] = 16384 + (c * 16 + l15) * 128;

#pragma unroll
  for (int t = 0; t < 4; t++) {
    const int nb = t & 1;
    const int kn = ((t + 1) & 3) * 64;
#pragma unroll
    for (int j = 0; j < 4; j++) {
      async_cp16(aSj[j] + kn, smem + (nb ^ 1) * 32768 + w * 4096 + j * 1024);
      async_cp16(bSj[j] + kn,
                 smem + (nb ^ 1) * 32768 + 16384 + w * 4096 + j * 1024);
    }
#pragma unroll
    for (int ks = 0; ks < 2; ks++) {
      const int sg = ks ? (sega ^ 64) : sega;
      short8 af[2], bf[8];
#pragma unroll
      for (int s = 0; s < 2; s++)
        af[s] = *(const short8*)(smem + nb * 32768 + aoff[s] + sg);
#pragma unroll
      for (int c = 0; c < 8; c++)
        bf[c] = *(const short8*)(smem + nb * 32768 + boff[c] + sg);
      if (g < 2) {
#pragma unroll
        for (int s = 0; s < 2; s++)
#pragma unroll
          for (int c = 0; c < 8; c++)
            acc[s][c] = MFMA16x32(bf[c], af[s], acc[s][c]);  // swapped
      } else {
#pragma unroll
        for (int s = 0; s < 2; s++)
#pragma unroll
          for (int c = 0; c < 8; c++)
            acc[s][c] = MFMA16x32(af[s], bf[c], acc[s][c]);
      }
    }
    __syncthreads();
  }

  if (g < 2) {
    unsigned short* O = g ? KH : QH;
    const float sc = g ? 1.0f : 0.17677669529663688f;  // 1/sqrt(32) into Q
#pragma unroll
    for (int s = 0; s < 2; s++)
#pragma unroll
      for (int c = 0; c < 8; c++) {
        const int row = m0 + w * 32 + s * 16 + l15;
        const int col = n0 + c * 16 + quad * 4;
        const int bb = row >> 12, nn = row & 4095;
        const int hh = col >> 5, dl = col & 31;
        u32x2 pk = {pack_bf16(acc[s][c][0] * sc, acc[s][c][1] * sc),
                    pack_bf16(acc[s][c][2] * sc, acc[s][c][3] * sc)};
        *(u32x2*)(O + ((size_t)(bb * 8 + hh) * 4096 + nn) * 32 + dl) = pk;
      }
  } else {
#pragma unroll
    for (int s = 0; s < 2; s++)
#pragma unroll
      for (int c = 0; c < 8; c++) {
        const int col = n0 + c * 16 + l15;  // h*32 + d
        const int hh = col >> 5, dl = col & 31;
        const int row = m0 + w * 32 + s * 16 + quad * 4;
        const int bb = row >> 12, nn = row & 4095;
        u32x2 pk = {pack_bf16(acc[s][c][0], acc[s][c][1]),
                    pack_bf16(acc[s][c][2], acc[s][c][3])};
        *(u32x2*)(VT + (size_t)((bb * 8 + hh) * 32 + dl) * 4096 + nn) = pk;
      }
  }
}

// ---------------------------------------------------------------------------
// Kernel 2: attention. Block = 256 thr (4 waves), one (b,h) x 256 q; wave owns
// 64 q (2 groups of 32). Grid 512 = 32 bh x 16 qt -> 2 blocks/CU.
// Iter = 128 keys. K tile 8KB [key][4 subsegs], subseg p of key k stored at
// phys p ^ ((k>>1)&3) -> b128 reads CONFLICT-FREE (verified per 8-lane phase).
// V tile 8KB [d][16 x 16B blocks], block b of row d stored at phys b ^ (d&7)
// -> b64 reads 2-way max (free). All frag reads = precomputed lane addr + imm.
// S^T = K.Q^T (2x 32x32x16 chained); leaky+pack in regs; packed C/D reg-quads
// feed 32x32x8 PV directly. launch_bounds(256,2): VGPR headroom, no spill.
// ---------------------------------------------------------------------------
__global__ __launch_bounds__(256, 2) void attn_kernel(
    const unsigned short* __restrict__ QH, const unsigned short* __restrict__ KH,
    const unsigned short* __restrict__ VT, float* __restrict__ out) {
  constexpr int VREG = 8192;   // V region offset within a buffer
  constexpr int BUF = 16384;   // K 8KB + V 8KB
  __shared__ __align__(16) char smem[2 * BUF];
  const int tid = threadIdx.x;
  const int w = tid >> 6, lane = tid & 63, l31 = lane & 31, half = lane >> 5;
  const int bid = blockIdx.x;
  const int bh = bid & 31, qt = bid >> 5;  // XCD swizzle: bh fixed per XCD
  const int b = bh >> 3, h = bh & 7;
  const int qbase = qt * 256 + w * 64;     // 64 q per wave, q < 4096

  // Q frags: B-operand of 32x32x16: n=q=l31(+32*qg), k(d) = kh*16 + half*8 + j.
  const unsigned short* Qp =
      QH + ((size_t)bh * 4096 + qbase + l31) * 32 + half * 8;
  short8 qf[2][2];
#pragma unroll
  for (int qg = 0; qg < 2; qg++)
#pragma unroll
    for (int kh = 0; kh < 2; kh++)
      qf[qg][kh] = *(const short8*)(Qp + qg * 1024 + kh * 16);

  // --- staging sources (lane-permuted, offset=0 pointers only) ---
  // K: phys 16B-seg lin = w*128 + j*64 + lane -> key = lin>>2, p = lin&3;
  //    holds global subseg p ^ ((key>>1)&3). j=+1 -> key+16, same XOR.
  const int klin = w * 128 + lane;
  const int key0 = klin >> 2, p0 = klin & 3;
  const unsigned short* gK0 =
      KH + ((size_t)bh * 4096 + key0) * 32 + (p0 ^ ((key0 >> 1) & 3)) * 8;
  const unsigned short* gK1 = gK0 + 16 * 32;  // key0+16 (same subseg map)
  // V: phys 16B-block lin = w*128 + j*64 + lane -> d = lin>>4, blk = lin&15;
  //    holds global block blk ^ (d&7).
  const int vlin0 = w * 128 + lane;
  const int vd0 = vlin0 >> 4, vb0 = vlin0 & 15;
  const unsigned short* gV0 =
      VT + ((size_t)bh * 32 + vd0) * 4096 + (vb0 ^ (vd0 & 7)) * 8;
  const int vlin1 = vlin0 + 64;
  const int vd1 = vlin1 >> 4, vb1 = vlin1 & 15;
  const unsigned short* gV1 =
      VT + ((size_t)bh * 32 + vd1) * 4096 + (vb1 ^ (vd1 & 7)) * 8;
  const int ldsK0 = w * 2048, ldsK1 = w * 2048 + 1024;
  const int ldsV0 = VREG + w * 2048, ldsV1 = VREG + w * 2048 + 1024;

  // --- hoisted read bases (all frag reads = lane addr + compile-time imm) ---
  // K read: phys subseg half^((l31>>1)&3) holds logical subseg half (d 0..15);
  // kb1 = kb0^32 -> logical subseg half+2 (d 16..31). Conflict-free b128.
  const int kb0 = l31 * 64 + ((half ^ ((l31 >> 1) & 3)) * 16);
  const int kb1 = kb0 ^ 32;
  const char* ptrK0 = (const char*)smem + kb0;
  const char* ptrK1 = (const char*)smem + kb1;
  // V read: logical block c at phys (c&7)^(l31&7) + (c>>3)*8; 8B at +half*8.
  const char* ptrV[8];
#pragma unroll
  for (int j = 0; j < 8; j++)
    ptrV[j] = (const char*)smem + VREG + l31 * 256 + ((j ^ (l31 & 7)) * 16) +
              half * 8;

  // preload tile 0 -> buf 0
  async_cp16(gK0, smem + ldsK0);
  async_cp16(gK1, smem + ldsK1);
  async_cp16(gV0, smem + ldsV0);
  async_cp16(gV1, smem + ldsV1);
  gK0 += 4096; gK1 += 4096;  // 128 keys * 32 shorts
  gV0 += 128;  gV1 += 128;   // 128 keys
  __syncthreads();

  f32x16 z16, acc[2];
#pragma unroll
  for (int i = 0; i < 16; i++) { z16[i] = 0.f; acc[0][i] = 0.f; acc[1][i] = 0.f; }

#define ATTN_BODY(B_)                                                         \
  {                                                                           \
    async_cp16(gK0, smem + ((B_) ^ 1) * BUF + ldsK0);                         \
    async_cp16(gK1, smem + ((B_) ^ 1) * BUF + ldsK1);                         \
    async_cp16(gV0, smem + ((B_) ^ 1) * BUF + ldsV0);                         \
    async_cp16(gV1, smem + ((B_) ^ 1) * BUF + ldsV1);                         \
    gK0 += 4096; gK1 += 4096; gV0 += 128; gV1 += 128;                         \
    _Pragma("unroll") for (int kt = 0; kt < 4; kt++) {                        \
      short8 kf0 = *(const short8*)(ptrK0 + (B_)*BUF + kt * 2048);            \
      short8 kf1 = *(const short8*)(ptrK1 + (B_)*BUF + kt * 2048);            \
      short4v vf[4];                                                          \
      _Pragma("unroll") for (int g = 0; g < 4; g++) {                         \
        const int c = kt * 4 + g;                                             \
        vf[g] = *(const short4v*)(ptrV[c & 7] + (B_)*BUF + (c >> 3) * 128);   \
      }                                                                       \
      _Pragma("unroll") for (int qg = 0; qg < 2; qg++) {                      \
        f32x16 st = MFMA32x16(kf0, qf[qg][0], z16);                           \
        st = MFMA32x16(kf1, qf[qg][1], st);                                   \
        _Pragma("unroll") for (int g = 0; g < 4; g++) {                       \
          u32x2 pk = {pack_bf16(lk(st[4 * g + 0]), lk(st[4 * g + 1])),        \
                      pack_bf16(lk(st[4 * g + 2]), lk(st[4 * g + 3]))};       \
          acc[qg] = mfma32x8(vf[g], __builtin_bit_cast(short4v, pk),          \
                             acc[qg]);                                        \
        }                                                                     \
      }                                                                       \
    }                                                                         \
    __syncthreads();                                                          \
  }

  for (int it = 0; it < 32; it += 2) {
    ATTN_BODY(0)
    ATTN_BODY(1)
  }
#undef ATTN_BODY

  // Epilogue: O^T row=d=8g+4*half+(reg&3), col=q=qbase+qg*32+l31.
#pragma unroll
  for (int qg = 0; qg < 2; qg++)
#pragma unroll
    for (int g = 0; g < 4; g++) {
      f32x4 o = {acc[qg][4 * g + 0], acc[qg][4 * g + 1], acc[qg][4 * g + 2],
                 acc[qg][4 * g + 3]};
      *(f32x4*)(out + ((size_t)b * 4096 + qbase + qg * 32 + l31) * 256 +
                h * 32 + g * 8 + half * 4) = o;
    }
}

// ---------------------------------------------------------------------------
extern "C" void kernel_launch(void* const* d_in, const int* in_sizes, int n_in,
                              void* d_out, int out_size, void* d_ws,
                              size_t ws_size, hipStream_t stream) {
  const float* x = (const float*)d_in[0];
  const float* Wq = (const float*)d_in[1];
  const float* Wk = (const float*)d_in[2];
  const float* Wv = (const float*)d_in[3];
  float* out = (float*)d_out;

  // Workspace (bf16): QH | KH | VT | xb | WT  (~33.5 MB). Order matters:
  // attn's final wrap-prefetch reads a few KB past KH/VT ends -> must land in
  // the next ws region (KH->VT, VT->xb), never past ws.
  unsigned short* ws = (unsigned short*)d_ws;
  unsigned short* QHb = ws;                // 32 bh * 4096 n * 32 d
  unsigned short* KHb = ws + 4194304;      // 32 bh * 4096 n * 32 d
  unsigned short* VTb = ws + 2 * 4194304;  // 32 bh * 32 d * 4096 n
  unsigned short* xbb = ws + 3 * 4194304;  // 16384*256
  unsigned short* WTb = ws + 4 * 4194304;  // 3 * 256 * 256

  prep_kernel<<<4288, 256, 0, stream>>>(x, Wq, Wk, Wv, xbb, WTb);
  proj_kernel<<<768, 256, 0, stream>>>(xbb, WTb, QHb, KHb, VTb);
  attn_kernel<<<512, 256, 0, stream>>>(QHb, KHb, VTb, out);
}